// Round 2
// baseline (497.896 us; speedup 1.0000x reference)
//
#include <hip/hip_runtime.h>

#define H   1024
#define S   64
#define V   32000
#define EMB 1088
#define GIN 2112

// workspace layout (float32 elements)
#define WS_X    0        // 2112  : x = [loc|emb_tail|prev_context]
#define WS_GI   2112     // 3072
#define WS_GH   5184     // 3072
#define WS_JOIN 8256     // 2048  : [h_new | attn_context]
#define WS_SG   10304    // 32000 : score_g
#define WS_SC   42304    // 64    : score_c (contiguous after SG)
#define WS_LOGZ 42368    // 1
#define WS_FLAG 42369    // 1 int : 1 = data is bf16, 0 = data is f32

typedef unsigned short ushort_t;
typedef unsigned int   uint_t;

__device__ __forceinline__ float b2f(ushort_t u) {
  union { uint_t i; float f; } v; v.i = ((uint_t)u) << 16; return v.f;
}
__device__ __forceinline__ float bl(uint_t u) {
  union { uint_t i; float f; } v; v.i = u << 16; return v.f;
}
__device__ __forceinline__ float bh(uint_t u) {
  union { uint_t i; float f; } v; v.i = u & 0xffff0000u; return v.f;
}
__device__ __forceinline__ ushort_t f2b(float f) {
  union { float f; uint_t u; } v; v.f = f;
  uint_t u = v.u;
  u += 0x7fffu + ((u >> 16) & 1u);   // RNE
  return (ushort_t)(u >> 16);
}

struct L8 { float v[8]; };

template<bool B>
__device__ __forceinline__ L8 load8(const void* base, size_t idx) {
  L8 r;
  if (B) {
    uint4 pk = *(const uint4*)((const ushort_t*)base + idx);
    r.v[0]=bl(pk.x); r.v[1]=bh(pk.x); r.v[2]=bl(pk.y); r.v[3]=bh(pk.y);
    r.v[4]=bl(pk.z); r.v[5]=bh(pk.z); r.v[6]=bl(pk.w); r.v[7]=bh(pk.w);
  } else {
    const float4* p = (const float4*)((const float*)base + idx);
    float4 a = p[0], b = p[1];
    r.v[0]=a.x; r.v[1]=a.y; r.v[2]=a.z; r.v[3]=a.w;
    r.v[4]=b.x; r.v[5]=b.y; r.v[6]=b.z; r.v[7]=b.w;
  }
  return r;
}
template<bool B>
__device__ __forceinline__ float ld1(const void* base, size_t idx) {
  return B ? b2f(((const ushort_t*)base)[idx]) : ((const float*)base)[idx];
}
template<bool B>
__device__ __forceinline__ void st1(void* base, size_t idx, float f) {
  if (B) ((ushort_t*)base)[idx] = f2b(f);
  else   ((float*)base)[idx] = f;
}
__device__ __forceinline__ float dot8f(L8 w, const float* xp) {
  const float4* p = (const float4*)xp;
  float4 a = p[0], b = p[1];
  return w.v[0]*a.x + w.v[1]*a.y + w.v[2]*a.z + w.v[3]*a.w
       + w.v[4]*b.x + w.v[5]*b.y + w.v[6]*b.z + w.v[7]*b.w;
}
__device__ __forceinline__ int ws_flag(const float* ws) {
  return *(const int*)(ws + WS_FLAG);
}

// ---------------- K0: dtype detect + build x vector + zero score_c ----------------
__global__ void k_prep(const int* word_input, const void* prev_context,
                       const int* sources, const int* targets, const int* ti,
                       const int* utf, const void* emb_table, const void* gen_W,
                       float* ws) {
  int tid = threadIdx.x;  // 256 threads, 1 block
  __shared__ float s_loc[S];
  __shared__ int s_di;
  __shared__ int s_flag;
  // --- dtype detection (wave 0): even-index u16s of gen_W viewed as bf16.
  // bf16 data -> ~all plausible; f32 data -> low mantissa halves, ~7% plausible.
  if (tid < 64) {
    const ushort_t* g = (const ushort_t*)gen_W;
    int cnt = 0;
#pragma unroll
    for (int k = 0; k < 4; ++k) {
      float a = fabsf(b2f(g[2 * (tid + 64 * k)]));
      if (a >= 1e-5f && a <= 1.0f) ++cnt;
    }
#pragma unroll
    for (int off = 32; off; off >>= 1) cnt += __shfl_down(cnt, off);
    if (tid == 0) {
      int isb = (cnt >= 128) ? 1 : 0;   // of 256 samples
      s_flag = isb;
      *(int*)(ws + WS_FLAG) = isb;
    }
  }
  if (tid == 0) s_di = utf[0] ? targets[ti[0]] : word_input[0];
  __syncthreads();
  int di = s_di;
  int FB = s_flag;
  if (tid < 64) {
    bool m = (sources[tid] == di);
    unsigned long long bal = __ballot(m);
    int c = __popcll(bal);
    float inv = (c > 0) ? (1.0f / sqrtf((float)c)) : 0.0f;
    s_loc[tid] = m ? inv : 0.0f;
    ws[WS_SC + tid] = 0.0f;
  }
  __syncthreads();
  int w = word_input[0];
  size_t eoff = (size_t)w * EMB;
  for (int i = tid; i < GIN; i += 256) {
    float v;
    if (i < S)        v = s_loc[i];
    else if (i < EMB) v = FB ? ld1<true>(emb_table, eoff + i)
                             : ld1<false>(emb_table, eoff + i);
    else              v = FB ? ld1<true>(prev_context, i - EMB)
                             : ld1<false>(prev_context, i - EMB);
    ws[WS_X + i] = v;
  }
}

// ---------------- K1: gi = Wih@x + bih, gh = Whh@h + bhh (one wave/row) ----------------
template<bool B>
__device__ __forceinline__ void gru_body(const void* Wih, const void* Whh,
    const void* bih, const void* bhh, const void* ph, float* ws,
    float* s_x, float* s_h) {
  int tid = threadIdx.x;
  for (int i = tid; i < GIN; i += 256) s_x[i] = ws[WS_X + i];
  for (int i = tid; i < H;   i += 256) s_h[i] = ld1<B>(ph, i);
  __syncthreads();
  int wave = tid >> 6, lane = tid & 63;
  int r = blockIdx.x * 4 + wave;        // grid 768 -> 3072 rows
  size_t ro = (size_t)r * GIN;
  float sum1 = 0.f;
#pragma unroll
  for (int it = 0; it < 4; ++it) {
    int j = it * 512 + lane * 8;
    sum1 += dot8f(load8<B>(Wih, ro + j), s_x + j);
  }
  sum1 += ld1<B>(Wih, ro + 2048 + lane) * s_x[2048 + lane];
  size_t ho = (size_t)r * H;
  float sum2 = 0.f;
#pragma unroll
  for (int it = 0; it < 2; ++it) {
    int j = it * 512 + lane * 8;
    sum2 += dot8f(load8<B>(Whh, ho + j), s_h + j);
  }
#pragma unroll
  for (int off = 32; off; off >>= 1) {
    sum1 += __shfl_down(sum1, off);
    sum2 += __shfl_down(sum2, off);
  }
  if (lane == 0) {
    ws[WS_GI + r] = sum1 + ld1<B>(bih, r);
    ws[WS_GH + r] = sum2 + ld1<B>(bhh, r);
  }
}
__launch_bounds__(256)
__global__ void k_gru(const void* Wih, const void* Whh, const void* bih,
                      const void* bhh, const void* ph, float* ws) {
  __shared__ float s_x[GIN];
  __shared__ float s_h[H];
  if (ws_flag(ws)) gru_body<true >(Wih, Whh, bih, bhh, ph, ws, s_x, s_h);
  else             gru_body<false>(Wih, Whh, bih, bhh, ph, ws, s_x, s_h);
}

// ---------------- K2: GRU gate nonlinearity -> h_new ----------------
template<bool B>
__device__ __forceinline__ void hnew_body(const void* ph, float* ws, void* d_out) {
  int i = blockIdx.x * 256 + threadIdx.x;   // grid 4 -> 1024
  float gr = ws[WS_GI + i]       + ws[WS_GH + i];
  float gz = ws[WS_GI + H + i]   + ws[WS_GH + H + i];
  float r  = 1.f / (1.f + expf(-gr));
  float z  = 1.f / (1.f + expf(-gz));
  float n  = tanhf(ws[WS_GI + 2*H + i] + r * ws[WS_GH + 2*H + i]);
  float h  = ld1<B>(ph, i);
  float hn = (1.f - z) * n + z * h;
  ws[WS_JOIN + i] = hn;
  st1<B>(d_out, V + H + i, hn);             // current_hidden at 33024
}
__global__ void k_hnew(const void* ph, float* ws, void* d_out) {
  if (ws_flag(ws)) hnew_body<true >(ph, ws, d_out);
  else             hnew_body<false>(ph, ws, d_out);
}

// ---------------- K3: attention scores + softmax + context ----------------
template<bool B>
__device__ __forceinline__ void attn_body(const void* enc, float* ws, void* d_out,
                                          float* s_hn, float* s_sc, float* s_w) {
  int tid = threadIdx.x;
  s_hn[tid] = ws[WS_JOIN + tid];
  __syncthreads();
  int wave = tid >> 6, lane = tid & 63;
#pragma unroll
  for (int q = 0; q < 4; ++q) {
    int s = wave + 16 * q;
    size_t eo = (size_t)s * H;
    float sum = 0.f;
#pragma unroll
    for (int it = 0; it < 2; ++it) {
      int j = it * 512 + lane * 8;
      sum += dot8f(load8<B>(enc, eo + j), s_hn + j);
    }
#pragma unroll
    for (int off = 32; off; off >>= 1) sum += __shfl_down(sum, off);
    if (lane == 0) s_sc[s] = sum;
  }
  __syncthreads();
  if (tid < 64) {
    float v = s_sc[tid];
    float m = v;
#pragma unroll
    for (int off = 32; off; off >>= 1) m = fmaxf(m, __shfl_xor(m, off));
    float e = expf(v - m);
    float sm = e;
#pragma unroll
    for (int off = 32; off; off >>= 1) sm += __shfl_xor(sm, off);
    float w = e / sm;
    s_w[tid] = w;
    st1<B>(d_out, V + 2*H + tid, w);        // attn_weights at 34048
  }
  __syncthreads();
  float acc = 0.f;
  for (int s = 0; s < S; ++s) acc += s_w[s] * ld1<B>(enc, (size_t)s * H + tid);
  ws[WS_JOIN + H + tid] = acc;
  st1<B>(d_out, V + tid, acc);              // attn_context at 32000
}
__launch_bounds__(1024)
__global__ void k_attn(const void* enc, float* ws, void* d_out) {
  __shared__ float s_hn[H];
  __shared__ float s_sc[S];
  __shared__ float s_w[S];
  if (ws_flag(ws)) attn_body<true >(enc, ws, d_out, s_hn, s_sc, s_w);
  else             attn_body<false>(enc, ws, d_out, s_hn, s_sc, s_w);
}

// ---------------- K4: copy-attention score_c (8s x 8hh tile per wave) ----------------
template<bool B>
__device__ __forceinline__ void copy_body(const void* enc, const void* copy_W,
    const void* copy_b, const void* ph, float* ws, float* s_part) {
  int tid = threadIdx.x, wave = tid >> 6, lane = tid & 63;
  int sg = blockIdx.x >> 5;                 // 0..7
  int s0 = sg * 8;
  int hh0 = (((blockIdx.x & 31) * 4) + wave) * 8;   // 0..1016
  if (tid < 8) s_part[tid] = 0.f;
  __syncthreads();

  float acc[64];
#pragma unroll
  for (int k = 0; k < 64; ++k) acc[k] = 0.f;

#pragma unroll
  for (int it = 0; it < 2; ++it) {
    int j = it * 512 + lane * 8;
    L8 e[8];
#pragma unroll
    for (int si = 0; si < 8; ++si)
      e[si] = load8<B>(enc, (size_t)(s0 + si) * H + j);
#pragma unroll
    for (int hi = 0; hi < 8; ++hi) {
      L8 w = load8<B>(copy_W, (size_t)(hh0 + hi) * H + j);
#pragma unroll
      for (int si = 0; si < 8; ++si) {
        float t = 0.f;
#pragma unroll
        for (int q = 0; q < 8; ++q) t += w.v[q] * e[si].v[q];
        acc[si * 8 + hi] += t;
      }
    }
  }
  // butterfly transpose-reduce: lane L ends with full sum of acc[L]
#pragma unroll
  for (int st = 5; st >= 0; --st) {
    int n = 1 << st;
    bool hi = (lane & n) != 0;
#pragma unroll
    for (int i = 0; i < 32; ++i) {
      if (i < n) {
        float keep = hi ? acc[i + n] : acc[i];
        float send = hi ? acc[i] : acc[i + n];
        acc[i] = keep + __shfl_xor(send, n);
      }
    }
  }
  int hi_idx = lane & 7;
  int si = lane >> 3;
  int hh = hh0 + hi_idx;
  float val = tanhf(acc[0] + ld1<B>(copy_b, hh)) * ld1<B>(ph, hh);
  val += __shfl_xor(val, 1);
  val += __shfl_xor(val, 2);
  val += __shfl_xor(val, 4);
  if (hi_idx == 0) atomicAdd(&s_part[si], val);
  __syncthreads();
  if (tid < 8) atomicAdd(ws + WS_SC + s0 + tid, s_part[tid]);
}
__launch_bounds__(256)
__global__ void k_copy(const void* enc, const void* copy_W, const void* copy_b,
                       const void* ph, float* ws) {
  __shared__ float s_part[8];
  if (ws_flag(ws)) copy_body<true >(enc, copy_W, copy_b, ph, ws, s_part);
  else             copy_body<false>(enc, copy_W, copy_b, ph, ws, s_part);
}

// ---------------- K5: score_g = gen_W @ joined + gen_b ----------------
template<bool B>
__device__ __forceinline__ void gen_body(const void* gen_W, const void* gen_b,
                                         float* ws, float* s_j) {
  int tid = threadIdx.x;
  for (int i = tid; i < 2 * H; i += 256) s_j[i] = ws[WS_JOIN + i];
  __syncthreads();
  int wave = tid >> 6, lane = tid & 63;
  int v0 = blockIdx.x * 8 + wave * 2;       // grid 4000, 2 rows/wave
#pragma unroll
  for (int rr = 0; rr < 2; ++rr) {
    int v = v0 + rr;
    size_t ro = (size_t)v * (2 * H);
    float sum = 0.f;
#pragma unroll
    for (int it = 0; it < 4; ++it) {
      int j = it * 512 + lane * 8;
      sum += dot8f(load8<B>(gen_W, ro + j), s_j + j);
    }
#pragma unroll
    for (int off = 32; off; off >>= 1) sum += __shfl_down(sum, off);
    if (lane == 0) ws[WS_SG + v] = sum + ld1<B>(gen_b, v);
  }
}
__launch_bounds__(256)
__global__ void k_gen(const void* gen_W, const void* gen_b, float* ws) {
  __shared__ float s_j[2 * H];
  if (ws_flag(ws)) gen_body<true >(gen_W, gen_b, ws, s_j);
  else             gen_body<false>(gen_W, gen_b, ws, s_j);
}

// ---------------- K6: log-softmax normalizer over 32064 scores ----------------
__launch_bounds__(1024)
__global__ void k_lse(float* ws) {
  __shared__ float red[16];
  __shared__ float s_M;
  int tid = threadIdx.x;
  const float4* sc4 = (const float4*)(ws + WS_SG);   // 8016 float4 = 32064
  float m = -3.0e38f;
  for (int i = tid; i < 8016; i += 1024) {
    float4 v = sc4[i];
    m = fmaxf(m, fmaxf(fmaxf(v.x, v.y), fmaxf(v.z, v.w)));
  }
#pragma unroll
  for (int off = 32; off; off >>= 1) m = fmaxf(m, __shfl_xor(m, off));
  int wave = tid >> 6;
  if ((tid & 63) == 0) red[wave] = m;
  __syncthreads();
  if (tid == 0) {
    float mm = red[0];
    for (int i = 1; i < 16; ++i) mm = fmaxf(mm, red[i]);
    s_M = mm;
  }
  __syncthreads();
  float M = s_M;
  float sum = 0.f;
  for (int i = tid; i < 8016; i += 1024) {
    float4 v = sc4[i];
    sum += expf(v.x - M) + expf(v.y - M) + expf(v.z - M) + expf(v.w - M);
  }
#pragma unroll
  for (int off = 32; off; off >>= 1) sum += __shfl_xor(sum, off);
  if ((tid & 63) == 0) red[wave] = sum;
  __syncthreads();
  if (tid == 0) {
    float ss = 0.f;
    for (int i = 0; i < 16; ++i) ss += red[i];
    ws[WS_LOGZ] = M + logf(ss);
  }
}

// ---------------- K7: output = prob_g + scatter(prob_c) ----------------
template<bool B>
__device__ __forceinline__ void final_body(const int* sources, const float* ws,
                                           void* d_out, int* s_src, float* s_pc) {
  int tid = threadIdx.x;
  float logZ = ws[WS_LOGZ];
  if (tid < 64) {
    s_src[tid] = sources[tid];
    s_pc[tid] = ws[WS_SC + tid] - logZ;
  }
  __syncthreads();
  int v = blockIdx.x * 256 + tid;           // grid 125 -> 32000
  float acc = ws[WS_SG + v] - logZ;
#pragma unroll
  for (int i = 0; i < S; ++i) acc += (s_src[i] == v) ? s_pc[i] : 0.f;
  st1<B>(d_out, v, acc);
}
__global__ void k_final(const int* sources, const float* ws, void* d_out) {
  __shared__ int   s_src[S];
  __shared__ float s_pc[S];
  if (ws_flag(ws)) final_body<true >(sources, ws, d_out, s_src, s_pc);
  else             final_body<false>(sources, ws, d_out, s_src, s_pc);
}

extern "C" void kernel_launch(void* const* d_in, const int* in_sizes, int n_in,
                              void* d_out, int out_size, void* d_ws, size_t ws_size,
                              hipStream_t stream) {
  const int* word_input   = (const int*)d_in[0];
  const void* prev_context = d_in[1];
  const void* prev_hidden  = d_in[2];
  const void* enc          = d_in[3];
  const int* sources      = (const int*)d_in[4];
  const int* targets      = (const int*)d_in[5];
  const int* ti           = (const int*)d_in[6];
  const int* utf          = (const int*)d_in[7];
  const void* emb_table    = d_in[8];
  const void* gru_Wih      = d_in[9];
  const void* gru_Whh      = d_in[10];
  const void* gru_bih      = d_in[11];
  const void* gru_bhh      = d_in[12];
  const void* copy_W       = d_in[13];
  const void* copy_b       = d_in[14];
  const void* gen_W        = d_in[15];
  const void* gen_b        = d_in[16];
  float* ws = (float*)d_ws;

  k_prep <<<1,    256, 0, stream>>>(word_input, prev_context, sources, targets,
                                    ti, utf, emb_table, gen_W, ws);
  k_gru  <<<768,  256, 0, stream>>>(gru_Wih, gru_Whh, gru_bih, gru_bhh,
                                    prev_hidden, ws);
  k_hnew <<<4,    256, 0, stream>>>(prev_hidden, ws, d_out);
  k_attn <<<1,   1024, 0, stream>>>(enc, ws, d_out);
  k_copy <<<256,  256, 0, stream>>>(enc, copy_W, copy_b, prev_hidden, ws);
  k_gen  <<<4000, 256, 0, stream>>>(gen_W, gen_b, ws);
  k_lse  <<<1,   1024, 0, stream>>>(ws);
  k_final<<<125,  256, 0, stream>>>(sources, ws, d_out);
}

// Round 3
// 485.970 us; speedup vs baseline: 1.0245x; 1.0245x over previous
//
#include <hip/hip_runtime.h>

#define H   1024
#define S   64
#define V   32000
#define EMB 1088
#define GIN 2112

// workspace layout (float32 elements)
#define WS_GI   2112     // 3072
#define WS_GH   5184     // 3072
#define WS_JOIN 8256     // 2048  : [h_new | attn_context]
#define WS_SG   10304    // 32000 : score_g
#define WS_SC   42304    // 64    : score_c (reduced)
#define WS_LOGZ 42368    // 1
#define WS_FLAG 42369    // 1 int : 1 = bf16 data, 0 = f32 data
#define WS_SCP  42376    // 2048  : score_c partials [s][g] (64 x 32)

typedef unsigned short ushort_t;
typedef unsigned int   uint_t;

__device__ __forceinline__ float b2f(ushort_t u) {
  union { uint_t i; float f; } v; v.i = ((uint_t)u) << 16; return v.f;
}
__device__ __forceinline__ float bl(uint_t u) {
  union { uint_t i; float f; } v; v.i = u << 16; return v.f;
}
__device__ __forceinline__ float bh(uint_t u) {
  union { uint_t i; float f; } v; v.i = u & 0xffff0000u; return v.f;
}
__device__ __forceinline__ ushort_t f2b(float f) {
  union { float f; uint_t u; } v; v.f = f;
  uint_t u = v.u;
  u += 0x7fffu + ((u >> 16) & 1u);   // RNE
  return (ushort_t)(u >> 16);
}

struct L8 { float v[8]; };

template<bool B>
__device__ __forceinline__ L8 load8(const void* base, size_t idx) {
  L8 r;
  if (B) {
    uint4 pk = *(const uint4*)((const ushort_t*)base + idx);
    r.v[0]=bl(pk.x); r.v[1]=bh(pk.x); r.v[2]=bl(pk.y); r.v[3]=bh(pk.y);
    r.v[4]=bl(pk.z); r.v[5]=bh(pk.z); r.v[6]=bl(pk.w); r.v[7]=bh(pk.w);
  } else {
    const float4* p = (const float4*)((const float*)base + idx);
    float4 a = p[0], b = p[1];
    r.v[0]=a.x; r.v[1]=a.y; r.v[2]=a.z; r.v[3]=a.w;
    r.v[4]=b.x; r.v[5]=b.y; r.v[6]=b.z; r.v[7]=b.w;
  }
  return r;
}
template<bool B>
__device__ __forceinline__ float ld1(const void* base, size_t idx) {
  return B ? b2f(((const ushort_t*)base)[idx]) : ((const float*)base)[idx];
}
template<bool B>
__device__ __forceinline__ void st1(void* base, size_t idx, float f) {
  if (B) ((ushort_t*)base)[idx] = f2b(f);
  else   ((float*)base)[idx] = f;
}
__device__ __forceinline__ float dot8f(L8 w, const float* xp) {
  const float4* p = (const float4*)xp;
  float4 a = p[0], b = p[1];
  return w.v[0]*a.x + w.v[1]*a.y + w.v[2]*a.z + w.v[3]*a.w
       + w.v[4]*b.x + w.v[5]*b.y + w.v[6]*b.z + w.v[7]*b.w;
}
__device__ __forceinline__ int ws_flag(const float* ws) {
  return *(const int*)(ws + WS_FLAG);
}

// ================= K1: fused GRU-gates GEMV (blocks 0..767) + copy-attn
//                       score_c partials (blocks 768..1023) =================
template<bool B>
__device__ void gru_part(const void* Wih, const void* Whh, const void* bih,
                         const void* bhh, const void* ph, const void* emb_table,
                         const void* prev_context, const int* word_input,
                         const int* sources, int di, float* ws,
                         float* s_x, float* s_h, float* s_loc) {
  int tid = threadIdx.x;
  // loc vector (wave 0)
  if (tid < 64) {
    bool m = (sources[tid] == di);
    unsigned long long bal = __ballot(m);
    int c = __popcll(bal);
    float inv = (c > 0) ? (1.0f / sqrtf((float)c)) : 0.0f;
    s_loc[tid] = m ? inv : 0.0f;
  }
  __syncthreads();
  // build x = [loc | emb_tail | prev_context] directly in LDS
  int w = word_input[0];
  size_t eoff = (size_t)w * EMB;
  for (int i = tid; i < GIN; i += 256) {
    float v;
    if (i < S)        v = s_loc[i];
    else if (i < EMB) v = ld1<B>(emb_table, eoff + i);
    else              v = ld1<B>(prev_context, i - EMB);
    s_x[i] = v;
  }
  for (int i = tid; i < H; i += 256) s_h[i] = ld1<B>(ph, i);
  __syncthreads();
  int wave = tid >> 6, lane = tid & 63;
  int r = blockIdx.x * 4 + wave;        // 768 blocks -> 3072 rows
  size_t ro = (size_t)r * GIN;
  float sum1 = 0.f;
#pragma unroll
  for (int it = 0; it < 4; ++it) {
    int j = it * 512 + lane * 8;
    sum1 += dot8f(load8<B>(Wih, ro + j), s_x + j);
  }
  sum1 += ld1<B>(Wih, ro + 2048 + lane) * s_x[2048 + lane];
  size_t ho = (size_t)r * H;
  float sum2 = 0.f;
#pragma unroll
  for (int it = 0; it < 2; ++it) {
    int j = it * 512 + lane * 8;
    sum2 += dot8f(load8<B>(Whh, ho + j), s_h + j);
  }
#pragma unroll
  for (int off = 32; off; off >>= 1) {
    sum1 += __shfl_down(sum1, off);
    sum2 += __shfl_down(sum2, off);
  }
  if (lane == 0) {
    ws[WS_GI + r] = sum1 + ld1<B>(bih, r);
    ws[WS_GH + r] = sum2 + ld1<B>(bhh, r);
  }
}

template<bool B>
__device__ void copy_part(const void* enc, const void* copy_W,
                          const void* copy_b, const void* ph, float* ws,
                          float* s_part) {
  int tid = threadIdx.x, wave = tid >> 6, lane = tid & 63;
  int b = blockIdx.x - 768;                 // 0..255
  int sg = b >> 5;                          // 0..7
  int s0 = sg * 8;
  int g  = b & 31;                          // 0..31 : hh-group
  int hh0 = (g * 4 + wave) * 8;             // 0..1016
  if (tid < 8) s_part[tid] = 0.f;
  __syncthreads();

  float acc[64];
#pragma unroll
  for (int k = 0; k < 64; ++k) acc[k] = 0.f;

#pragma unroll
  for (int it = 0; it < 2; ++it) {
    int j = it * 512 + lane * 8;
    L8 e[8];
#pragma unroll
    for (int si = 0; si < 8; ++si)
      e[si] = load8<B>(enc, (size_t)(s0 + si) * H + j);
#pragma unroll
    for (int hi = 0; hi < 8; ++hi) {
      L8 w = load8<B>(copy_W, (size_t)(hh0 + hi) * H + j);
#pragma unroll
      for (int si = 0; si < 8; ++si) {
        float t = 0.f;
#pragma unroll
        for (int q = 0; q < 8; ++q) t += w.v[q] * e[si].v[q];
        acc[si * 8 + hi] += t;
      }
    }
  }
  // butterfly transpose-reduce: lane L ends with full sum of acc[L]
#pragma unroll
  for (int st = 5; st >= 0; --st) {
    int n = 1 << st;
    bool hi = (lane & n) != 0;
#pragma unroll
    for (int i = 0; i < 32; ++i) {
      if (i < n) {
        float keep = hi ? acc[i + n] : acc[i];
        float send = hi ? acc[i] : acc[i + n];
        acc[i] = keep + __shfl_xor(send, n);
      }
    }
  }
  int hi_idx = lane & 7;
  int si = lane >> 3;
  int hh = hh0 + hi_idx;
  float val = tanhf(acc[0] + ld1<B>(copy_b, hh)) * ld1<B>(ph, hh);
  val += __shfl_xor(val, 1);
  val += __shfl_xor(val, 2);
  val += __shfl_xor(val, 4);
  if (hi_idx == 0) atomicAdd(&s_part[si], val);
  __syncthreads();
  if (tid < 8)
    ws[WS_SCP + (size_t)(s0 + tid) * 32 + g] = s_part[tid];  // distinct slot
}

__launch_bounds__(256)
__global__ void k_main(const int* word_input, const void* prev_context,
                       const void* ph, const void* enc, const int* sources,
                       const int* targets, const int* ti, const int* utf,
                       const void* emb_table, const void* Wih, const void* Whh,
                       const void* bih, const void* bhh, const void* copy_W,
                       const void* copy_b, const void* gen_W, float* ws) {
  __shared__ float s_x[GIN];
  __shared__ float s_h[H];
  __shared__ float s_loc[S];
  __shared__ float s_part[8];
  __shared__ int s_flag, s_di;
  int tid = threadIdx.x;
  // per-block dtype detection on gen_W (deterministic, all blocks agree)
  if (tid < 64) {
    const ushort_t* g = (const ushort_t*)gen_W;
    int cnt = 0;
#pragma unroll
    for (int k = 0; k < 4; ++k) {
      float a = fabsf(b2f(g[2 * (tid + 64 * k)]));
      if (a >= 1e-5f && a <= 1.0f) ++cnt;
    }
#pragma unroll
    for (int off = 32; off; off >>= 1) cnt += __shfl_down(cnt, off);
    if (tid == 0) s_flag = (cnt >= 128) ? 1 : 0;
  }
  if (tid == 65) s_di = utf[0] ? targets[ti[0]] : word_input[0];
  __syncthreads();
  int FB = s_flag;
  if (blockIdx.x == 0 && tid == 0) *(int*)(ws + WS_FLAG) = FB;  // publish
  if (blockIdx.x < 768) {
    if (FB) gru_part<true >(Wih, Whh, bih, bhh, ph, emb_table, prev_context,
                            word_input, sources, s_di, ws, s_x, s_h, s_loc);
    else    gru_part<false>(Wih, Whh, bih, bhh, ph, emb_table, prev_context,
                            word_input, sources, s_di, ws, s_x, s_h, s_loc);
  } else {
    if (FB) copy_part<true >(enc, copy_W, copy_b, ph, ws, s_part);
    else    copy_part<false>(enc, copy_W, copy_b, ph, ws, s_part);
  }
}

// ================= K2: GRU nonlinearity -> h_new, then attention =================
template<bool B>
__device__ void mid_body(const void* ph, const void* enc, float* ws,
                         void* d_out, float* s_hn, float* s_sc, float* s_w) {
  int tid = threadIdx.x;   // 1024 threads, 1 block
  // --- h_new (elementwise over 1024 dims)
  {
    float gr = ws[WS_GI + tid]       + ws[WS_GH + tid];
    float gz = ws[WS_GI + H + tid]   + ws[WS_GH + H + tid];
    float r  = 1.f / (1.f + expf(-gr));
    float z  = 1.f / (1.f + expf(-gz));
    float n  = tanhf(ws[WS_GI + 2*H + tid] + r * ws[WS_GH + 2*H + tid]);
    float h  = ld1<B>(ph, tid);
    float hn = (1.f - z) * n + z * h;
    s_hn[tid] = hn;
    ws[WS_JOIN + tid] = hn;
    st1<B>(d_out, V + H + tid, hn);            // current_hidden at 33024
  }
  __syncthreads();
  // --- attention scores (16 waves x 4 rows)
  int wave = tid >> 6, lane = tid & 63;
#pragma unroll
  for (int q = 0; q < 4; ++q) {
    int s = wave + 16 * q;
    size_t eo = (size_t)s * H;
    float sum = 0.f;
#pragma unroll
    for (int it = 0; it < 2; ++it) {
      int j = it * 512 + lane * 8;
      sum += dot8f(load8<B>(enc, eo + j), s_hn + j);
    }
#pragma unroll
    for (int off = 32; off; off >>= 1) sum += __shfl_down(sum, off);
    if (lane == 0) s_sc[s] = sum;
  }
  __syncthreads();
  // --- softmax over 64 scores (wave 0)
  if (tid < 64) {
    float v = s_sc[tid];
    float m = v;
#pragma unroll
    for (int off = 32; off; off >>= 1) m = fmaxf(m, __shfl_xor(m, off));
    float e = expf(v - m);
    float sm = e;
#pragma unroll
    for (int off = 32; off; off >>= 1) sm += __shfl_xor(sm, off);
    float w = e / sm;
    s_w[tid] = w;
    st1<B>(d_out, V + 2*H + tid, w);           // attn_weights at 34048
  }
  __syncthreads();
  // --- context = attn_weights @ enc
  float acc = 0.f;
#pragma unroll 4
  for (int s = 0; s < S; ++s) acc += s_w[s] * ld1<B>(enc, (size_t)s * H + tid);
  ws[WS_JOIN + H + tid] = acc;
  st1<B>(d_out, V + tid, acc);                 // attn_context at 32000
}
__launch_bounds__(1024)
__global__ void k_mid(const void* ph, const void* enc, float* ws, void* d_out) {
  __shared__ float s_hn[H];
  __shared__ float s_sc[S];
  __shared__ float s_w[S];
  if (ws_flag(ws)) mid_body<true >(ph, enc, ws, d_out, s_hn, s_sc, s_w);
  else             mid_body<false>(ph, enc, ws, d_out, s_hn, s_sc, s_w);
}

// ================= K3: score_g = gen_W @ joined + gen_b =================
template<bool B>
__device__ void gen_body(const void* gen_W, const void* gen_b, float* ws,
                         float* s_j) {
  int tid = threadIdx.x;
  for (int i = tid; i < 2 * H; i += 256) s_j[i] = ws[WS_JOIN + i];
  __syncthreads();
  int wave = tid >> 6, lane = tid & 63;
  int v0 = blockIdx.x * 8 + wave * 2;       // grid 4000, 2 rows/wave
#pragma unroll
  for (int rr = 0; rr < 2; ++rr) {
    int v = v0 + rr;
    size_t ro = (size_t)v * (2 * H);
    float sum = 0.f;
#pragma unroll
    for (int it = 0; it < 4; ++it) {
      int j = it * 512 + lane * 8;
      sum += dot8f(load8<B>(gen_W, ro + j), s_j + j);
    }
#pragma unroll
    for (int off = 32; off; off >>= 1) sum += __shfl_down(sum, off);
    if (lane == 0) ws[WS_SG + v] = sum + ld1<B>(gen_b, v);
  }
}
__launch_bounds__(256)
__global__ void k_gen(const void* gen_W, const void* gen_b, float* ws) {
  __shared__ float s_j[2 * H];
  if (ws_flag(ws)) gen_body<true >(gen_W, gen_b, ws, s_j);
  else             gen_body<false>(gen_W, gen_b, ws, s_j);
}

// ================= K4: reduce score_c partials + log-sum-exp =================
__launch_bounds__(1024)
__global__ void k_lse(float* ws) {
  __shared__ float red[16];
  __shared__ float s_M;
  __shared__ float s_sc[S];
  int tid = threadIdx.x;
  // reduce 32 partials per source row
  if (tid < 64) {
    float sc = 0.f;
#pragma unroll
    for (int g = 0; g < 32; ++g) sc += ws[WS_SCP + (size_t)tid * 32 + g];
    s_sc[tid] = sc;
    ws[WS_SC + tid] = sc;
  }
  __syncthreads();
  const float4* sc4 = (const float4*)(ws + WS_SG);   // 8000 float4 = 32000
  float m = -3.0e38f;
  for (int i = tid; i < 8000; i += 1024) {
    float4 v = sc4[i];
    m = fmaxf(m, fmaxf(fmaxf(v.x, v.y), fmaxf(v.z, v.w)));
  }
  if (tid < 64) m = fmaxf(m, s_sc[tid]);
#pragma unroll
  for (int off = 32; off; off >>= 1) m = fmaxf(m, __shfl_xor(m, off));
  int wave = tid >> 6;
  if ((tid & 63) == 0) red[wave] = m;
  __syncthreads();
  if (tid == 0) {
    float mm = red[0];
    for (int i = 1; i < 16; ++i) mm = fmaxf(mm, red[i]);
    s_M = mm;
  }
  __syncthreads();
  float M = s_M;
  float sum = 0.f;
  for (int i = tid; i < 8000; i += 1024) {
    float4 v = sc4[i];
    sum += expf(v.x - M) + expf(v.y - M) + expf(v.z - M) + expf(v.w - M);
  }
  if (tid < 64) sum += expf(s_sc[tid] - M);
#pragma unroll
  for (int off = 32; off; off >>= 1) sum += __shfl_xor(sum, off);
  if ((tid & 63) == 0) red[wave] = sum;
  __syncthreads();
  if (tid == 0) {
    float ss = 0.f;
    for (int i = 0; i < 16; ++i) ss += red[i];
    ws[WS_LOGZ] = M + logf(ss);
  }
}

// ================= K5: output = prob_g + scatter(prob_c) =================
template<bool B>
__device__ void final_body(const int* sources, const float* ws, void* d_out,
                           int* s_src, float* s_pc) {
  int tid = threadIdx.x;
  float logZ = ws[WS_LOGZ];
  if (tid < 64) {
    s_src[tid] = sources[tid];
    s_pc[tid] = ws[WS_SC + tid] - logZ;
  }
  __syncthreads();
  int v = blockIdx.x * 256 + tid;           // grid 125 -> 32000
  float acc = ws[WS_SG + v] - logZ;
#pragma unroll
  for (int i = 0; i < S; ++i) acc += (s_src[i] == v) ? s_pc[i] : 0.f;
  st1<B>(d_out, v, acc);
}
__global__ void k_final(const int* sources, const float* ws, void* d_out) {
  __shared__ int   s_src[S];
  __shared__ float s_pc[S];
  if (ws_flag(ws)) final_body<true >(sources, ws, d_out, s_src, s_pc);
  else             final_body<false>(sources, ws, d_out, s_src, s_pc);
}

extern "C" void kernel_launch(void* const* d_in, const int* in_sizes, int n_in,
                              void* d_out, int out_size, void* d_ws, size_t ws_size,
                              hipStream_t stream) {
  const int*  word_input   = (const int*)d_in[0];
  const void* prev_context = d_in[1];
  const void* prev_hidden  = d_in[2];
  const void* enc          = d_in[3];
  const int*  sources      = (const int*)d_in[4];
  const int*  targets      = (const int*)d_in[5];
  const int*  ti           = (const int*)d_in[6];
  const int*  utf          = (const int*)d_in[7];
  const void* emb_table    = d_in[8];
  const void* gru_Wih      = d_in[9];
  const void* gru_Whh      = d_in[10];
  const void* gru_bih      = d_in[11];
  const void* gru_bhh      = d_in[12];
  const void* copy_W       = d_in[13];
  const void* copy_b       = d_in[14];
  const void* gen_W        = d_in[15];
  const void* gen_b        = d_in[16];
  float* ws = (float*)d_ws;

  k_main <<<1024, 256, 0, stream>>>(word_input, prev_context, prev_hidden, enc,
                                    sources, targets, ti, utf, emb_table,
                                    gru_Wih, gru_Whh, gru_bih, gru_bhh,
                                    copy_W, copy_b, gen_W, ws);
  k_mid  <<<1,   1024, 0, stream>>>(prev_hidden, enc, ws, d_out);
  k_gen  <<<4000, 256, 0, stream>>>(gen_W, gen_b, ws);
  k_lse  <<<1,   1024, 0, stream>>>(ws);
  k_final<<<125,  256, 0, stream>>>(sources, ws, d_out);
}